// Round 5
// baseline (147.370 us; speedup 1.0000x reference)
//
#include <hip/hip_runtime.h>
#include <math.h>

#define EDIM 100
#define KP   128          // padded K
#define NF   4000
#define NN   4000
#define NB   8
#define NP   4096         // padded N and F
#define BN   128          // n-rows per block
#define BF   64           // f per f-block
#define FPB  4            // f-blocks folded per main block
#define NYB  16           // 64 f-blocks / FPB

#define CONVB (3 * NP * 16 / 256)     // 768 convert blocks (short8 per thread)
#define PREPB 64                      // 64 P-blocks (one per 64-f group, all 8 b's)
#define E2B   ((NN + 255) / 256)      // 16 e2 blocks

typedef __attribute__((ext_vector_type(8))) short short8;
typedef __attribute__((ext_vector_type(4))) float floatx4;

// Static device scratch.
__device__ __align__(16) unsigned short g_A [NP * KP];   // ent  bf16, K-padded
__device__ __align__(16) unsigned short g_B1[NP * KP];   // fa1  bf16
__device__ __align__(16) unsigned short g_B2[NP * KP];   // fa2  bf16
// P in main-ready layout: [g][fblk 64][chunk 128][ft 4] floats, chunk = c*8 + b.
// (fold reads floatx4 at (c*8+b)*4 -- f = ft*16 + c)
__device__ __align__(16) float g_P2[2 * 64 * 512];
__device__ float g_e2[NN];
__device__ float g_part[2 * NB * NYB * NP];              // [g][b][yblk][n]  (4 MB)

__device__ __forceinline__ unsigned short f2bf(float x) {
    union { float f; unsigned int u; } v; v.f = x;
    unsigned int r = v.u + 0x7FFFu + ((v.u >> 16) & 1u);  // RNE
    return (unsigned short)(r >> 16);
}

// 16-lane min reduction via DPP mirrors: XOR-masks {15,7,3,1} span all 16 lanes.
__device__ __forceinline__ float row16_min(float x) {
    int i;
    i = __builtin_amdgcn_mov_dpp(__float_as_int(x), 0x140, 0xF, 0xF, false); // row_mirror (^15)
    x = fminf(x, __int_as_float(i));
    i = __builtin_amdgcn_mov_dpp(__float_as_int(x), 0x141, 0xF, 0xF, false); // row_half_mirror (^7)
    x = fminf(x, __int_as_float(i));
    i = __builtin_amdgcn_mov_dpp(__float_as_int(x), 0x1B, 0xF, 0xF, false);  // quad reverse (^3)
    x = fminf(x, __int_as_float(i));
    i = __builtin_amdgcn_mov_dpp(__float_as_int(x), 0xB1, 0xF, 0xF, false);  // quad swap (^1)
    x = fminf(x, __int_as_float(i));
    return x;
}

// ---- merged prep: convert (768 blk) | P (64 blk, coalesced) | e2 (16 blk) ----
__global__ void prep(const float* __restrict__ rel,  const float* __restrict__ arg1,
                     const float* __restrict__ arg2, const float* __restrict__ frel,
                     const float* __restrict__ fa1,  const float* __restrict__ fa2,
                     const float* __restrict__ ent) {
    __shared__ float sF[64 * 101];              // 25.9 KB, stride 101 (2-way bank max)
    const int bx = blockIdx.x;
    const int t  = threadIdx.x;

    if (bx < CONVB) {
        // fp32 [4000][100] -> bf16 [4096][128], one short8 (8 cols) per thread
        int plane = bx >> 8;                    // 256 blocks per plane
        int local = ((bx & 255) << 8) | t;      // 0 .. NP*16-1
        int row = local >> 4, j = local & 15;   // j = 8-col chunk
        const float* src = (plane == 0) ? ent : (plane == 1) ? fa1 : fa2;
        unsigned short* dst = (plane == 0) ? g_A : (plane == 1) ? g_B1 : g_B2;
        short8 o = (short8){0, 0, 0, 0, 0, 0, 0, 0};
        if (row < NF && j <= 12) {
            if (j < 12) {
                float4 v0 = *(const float4*)(src + row * EDIM + j * 8);
                float4 v1 = *(const float4*)(src + row * EDIM + j * 8 + 4);
                o[0] = (short)f2bf(v0.x); o[1] = (short)f2bf(v0.y);
                o[2] = (short)f2bf(v0.z); o[3] = (short)f2bf(v0.w);
                o[4] = (short)f2bf(v1.x); o[5] = (short)f2bf(v1.y);
                o[6] = (short)f2bf(v1.z); o[7] = (short)f2bf(v1.w);
            } else {  // j == 12: cols 96..99 valid, 100..103 zero
                float4 v0 = *(const float4*)(src + row * EDIM + 96);
                o[0] = (short)f2bf(v0.x); o[1] = (short)f2bf(v0.y);
                o[2] = (short)f2bf(v0.z); o[3] = (short)f2bf(v0.w);
            }
        }
        *(short8*)(dst + row * KP + j * 8) = o;
    } else if (bx < CONVB + PREPB) {
        // P for one 64-f group, ALL 8 b's.  3 passes (frel/fa1/fa2): stage 64x100
        // floats coalesced into LDS, then thread (fl = t&63, bq = t>>6) computes
        // dots for b = bq and bq+4 via LDS broadcast + wave-uniform s_loads.
        const int fbx = bx - CONVB;             // 0..63
        const int fl = t & 63;
        const int bq = t >> 6;                  // 0..3; owns b = bq, bq+4
        const int f  = fbx * 64 + fl;

        float nf = 0.f;
        float dr[2], d1[2], d2[2], qr[2], q1n[2], q2n[2];

        #pragma unroll 3
        for (int pass = 0; pass < 3; pass++) {
            const float* src = (pass == 0) ? frel : (pass == 1) ? fa1 : fa2;
            const float* qv  = (pass == 0) ? rel  : (pass == 1) ? arg1 : arg2;
            __syncthreads();                    // previous pass's reads done
            #pragma unroll
            for (int i = 0; i < 25; i++) {      // 6400 floats, coalesced
                int idx = i * 256 + t;
                int row = idx / 100, col = idx - row * 100;
                int fr = fbx * 64 + row; if (fr > NF - 1) fr = NF - 1;
                sF[row * 101 + col] = src[fr * EDIM + col];
            }
            __syncthreads();
            float dot0 = 0.f, dot1 = 0.f, qn0 = 0.f, qn1 = 0.f, fn = 0.f;
            #pragma unroll 4
            for (int k = 0; k < EDIM; k++) {
                float fv = sF[fl * 101 + k];
                float u0 = qv[bq * EDIM + k];          // wave-uniform -> s_load
                float u1 = qv[(bq + 4) * EDIM + k];
                dot0 = fmaf(fv, u0, dot0);
                dot1 = fmaf(fv, u1, dot1);
                qn0  = fmaf(u0, u0, qn0);
                qn1  = fmaf(u1, u1, qn1);
                fn   = fmaf(fv, fv, fn);
            }
            nf += fn;
            if (pass == 0) { dr[0] = dot0; dr[1] = dot1; qr[0] = qn0; qr[1] = qn1; }
            else if (pass == 1) { d1[0] = dot0; d1[1] = dot1; q1n[0] = qn0; q1n[1] = qn1; }
            else { d2[0] = dot0; d2[1] = dot1; q2n[0] = qn0; q2n[1] = qn1; }
        }

        const int cc = fl & 15;                 // f & 15
        const int ft = fl >> 4;                 // (f & 63) >> 4
        #pragma unroll
        for (int bi = 0; bi < 2; bi++) {
            int b = bq + bi * 4;
            float psp = nf + qr[bi] + q1n[bi] - 2.f * (dr[bi] + d1[bi]);
            float ppo = nf + qr[bi] + q2n[bi] - 2.f * (dr[bi] + d2[bi]);
            if (f >= NF) { psp = __builtin_inff(); ppo = __builtin_inff(); }
            int chunk = cc * 8 + b;
            g_P2[(0 * 64 + fbx) * 512 + chunk * 4 + ft] = psp;
            g_P2[(1 * 64 + fbx) * 512 + chunk * 4 + ft] = ppo;
        }
    } else {
        int n = (bx - CONVB - PREPB) * 256 + t;
        if (n < NN) {
            const float4* ep = (const float4*)(ent + n * EDIM);
            float s = 0.f;
            #pragma unroll
            for (int i = 0; i < EDIM / 4; i++) {
                float4 v = ep[i];
                s += v.x * v.x + v.y * v.y + v.z * v.z + v.w * v.w;
            }
            g_e2[n] = s;
        }
    }
}

// Main: grid (32, 16, 2); z = g.  Per block: 128 n-rows, FPB=4 f-blocks of 64.
// NO LDS, NO barriers: A fragments in registers; B fragments and P read
// directly from global (entire working set ~2.3 MB is L2-resident per XCD;
// each B-fragment instruction consumes 16 full 64-B lines).  Latency hidden
// by 12 waves/CU (launch_bounds(256,3)).  P folded in MFMA acc layout;
// running min in 64 VGPRs; DPP c-reduce once at the end.
__global__ void __launch_bounds__(256, 3) main_kernel() {
    const int t = threadIdx.x;
    const int n0 = blockIdx.x * BN;
    const int by = blockIdx.y;
    const int g  = blockIdx.z;
    const int lane = t & 63;
    const int c = lane & 15;
    const int q = lane >> 4;
    const int w = t >> 6;
    const int w32 = w * 32;

    const unsigned short* gB = g ? g_B1 : g_B2;  // g=0(sp): entity . fa2; g=1(po): . fa1

    // A fragments, hoisted across all f-blocks (32 VGPR).
    short8 afrag[2][4];                          // [mt][s]
    #pragma unroll
    for (int mt = 0; mt < 2; mt++)
        #pragma unroll
        for (int s = 0; s < 4; s++)
            afrag[mt][s] = *(const short8*)(g_A + (n0 + w32 + mt * 16 + c) * KP + (s * 4 + q) * 8);

    floatx4 m2[NB][2];                           // [b][mt] running min (64 VGPR)
    #pragma unroll
    for (int b = 0; b < NB; b++)
        #pragma unroll
        for (int mt = 0; mt < 2; mt++)
            m2[b][mt] = (floatx4){__builtin_inff(), __builtin_inff(),
                                  __builtin_inff(), __builtin_inff()};

    #pragma unroll 1
    for (int ib = 0; ib < FPB; ib++) {
        const int fb = by * FPB + ib;
        const int f0 = fb * BF;

        floatx4 acc[2][4];                       // [mt][ft]
        #pragma unroll
        for (int mt = 0; mt < 2; mt++)
            #pragma unroll
            for (int ft = 0; ft < 4; ft++)
                acc[mt][ft] = (floatx4){0.f, 0.f, 0.f, 0.f};

        #pragma unroll
        for (int s = 0; s < 4; s++) {            // K-steps of 32
            #pragma unroll
            for (int ft = 0; ft < 4; ft++) {
                short8 bb = *(const short8*)(gB + (f0 + ft * 16 + c) * KP + (s * 4 + q) * 8);
                acc[0][ft] = __builtin_amdgcn_mfma_f32_16x16x32_bf16(afrag[0][s], bb, acc[0][ft], 0, 0, 0);
                acc[1][ft] = __builtin_amdgcn_mfma_f32_16x16x32_bf16(afrag[1][s], bb, acc[1][ft], 0, 0, 0);
            }
        }

        // ---- fold P in acc layout: f = ft*16 + c; one global b128 per b ----
        const float* Pf = g_P2 + (g * 64 + fb) * 512;
        #pragma unroll
        for (int b = 0; b < NB; b++) {
            floatx4 p = *(const floatx4*)(Pf + (c * 8 + b) * 4);
            #pragma unroll
            for (int mt = 0; mt < 2; mt++) {
                #pragma unroll
                for (int r = 0; r < 4; r++) {
                    float t0 = fmaf(-2.f, acc[mt][0][r], p[0]);
                    float t1 = fmaf(-2.f, acc[mt][1][r], p[1]);
                    float t2 = fmaf(-2.f, acc[mt][2][r], p[2]);
                    float t3 = fmaf(-2.f, acc[mt][3][r], p[3]);
                    float u = fminf(fminf(t0, t1), t2);                   // v_min3
                    m2[b][mt][r] = fminf(fminf(u, t3), m2[b][mt][r]);     // v_min3
                }
            }
        }
    }

    // ---- once: reduce over 16 c-lanes (DPP, pure VALU) ----
    #pragma unroll
    for (int b = 0; b < NB; b++)
        #pragma unroll
        for (int mt = 0; mt < 2; mt++)
            #pragma unroll
            for (int r = 0; r < 4; r++)
                m2[b][mt][r] = row16_min(m2[b][mt][r]);

    if (c == 0) {
        #pragma unroll
        for (int b = 0; b < NB; b++)
            #pragma unroll
            for (int mt = 0; mt < 2; mt++)
                *(float4*)&g_part[((g * NB + b) * NYB + by) * NP +
                                  n0 + w32 + mt * 16 + q * 4] =
                    (float4){m2[b][mt][0], m2[b][mt][1], m2[b][mt][2], m2[b][mt][3]};
    }
}

__global__ void finalize(float* __restrict__ out) {
    int idx = blockIdx.x * 256 + threadIdx.x;   // over 2*NB*NN, out layout (g*NB+b)*NN+n
    if (idx >= 2 * NB * NN) return;
    int sb = idx / NN;
    int n = idx % NN;
    float m = __builtin_inff();
    #pragma unroll
    for (int j = 0; j < NYB; j += 2) {
        float a = g_part[(sb * NYB + j) * NP + n];
        float b = g_part[(sb * NYB + j + 1) * NP + n];
        m = fminf(m, fminf(a, b));              // v_min3
    }
    float d2 = fmaxf(m + g_e2[n], 0.f);
    out[idx] = expf(-0.5f * d2);
}

extern "C" void kernel_launch(void* const* d_in, const int* in_sizes, int n_in,
                              void* d_out, int out_size, void* d_ws, size_t ws_size,
                              hipStream_t stream) {
    const float* rel  = (const float*)d_in[0];
    const float* arg1 = (const float*)d_in[1];
    const float* arg2 = (const float*)d_in[2];
    const float* frel = (const float*)d_in[3];
    const float* fa1  = (const float*)d_in[4];
    const float* fa2  = (const float*)d_in[5];
    const float* ent  = (const float*)d_in[6];
    float* out = (float*)d_out;

    prep<<<dim3(CONVB + PREPB + E2B), 256, 0, stream>>>(rel, arg1, arg2, frel, fa1, fa2, ent);
    main_kernel<<<dim3(NP / BN, NYB, 2), 256, 0, stream>>>();
    finalize<<<(2 * NB * NN + 255) / 256, 256, 0, stream>>>(out);
}

// Round 6
// 126.815 us; speedup vs baseline: 1.1621x; 1.1621x over previous
//
#include <hip/hip_runtime.h>
#include <math.h>

#define EDIM 100
#define KP   128          // padded K
#define NF   4000
#define NN   4000
#define NB   8
#define NP   4096         // padded N and F
#define BN   128          // n-rows per block
#define BF   64           // f per f-block
#define FPB  4            // f-blocks folded per main block
#define NYB  16           // 64 f-blocks / FPB

#define CONVB (3 * NP * 16 / 256)     // 768 convert blocks (short8 per thread)
#define PREPB 64                      // 64 P-blocks (one per 64-f group, all 8 b's)
#define E2B   ((NN + 255) / 256)      // 16 e2 blocks

typedef __attribute__((ext_vector_type(8))) short short8;
typedef __attribute__((ext_vector_type(4))) float floatx4;

typedef const __attribute__((address_space(1))) unsigned int* gas_u32;
typedef __attribute__((address_space(3))) unsigned int* las_u32;

// Static device scratch.
__device__ __align__(16) unsigned short g_A [NP * KP];   // ent  bf16, K-padded
__device__ __align__(16) unsigned short g_B1[NP * KP];   // fa1  bf16
__device__ __align__(16) unsigned short g_B2[NP * KP];   // fa2  bf16
// P in main-ready layout: [g][fblk 64][chunk 128][ft 4] floats.
// chunk = c*8 + (b ^ (c&7))  -- XOR spreads the LDS fold-read over 8 bank
// quartets (2-way max = free); without it all 16 c-lanes hit one quartet.
__device__ __align__(16) float g_P2[2 * 64 * 512];
__device__ float g_e2[NN];
__device__ float g_part[2 * NB * NYB * NP];              // [g][b][yblk][n]  (4 MB)

__device__ __forceinline__ unsigned short f2bf(float x) {
    union { float f; unsigned int u; } v; v.f = x;
    unsigned int r = v.u + 0x7FFFu + ((v.u >> 16) & 1u);  // RNE
    return (unsigned short)(r >> 16);
}

// 16-lane min reduction via DPP mirrors: XOR-masks {15,7,3,1} span all 16 lanes.
__device__ __forceinline__ float row16_min(float x) {
    int i;
    i = __builtin_amdgcn_mov_dpp(__float_as_int(x), 0x140, 0xF, 0xF, false); // row_mirror (^15)
    x = fminf(x, __int_as_float(i));
    i = __builtin_amdgcn_mov_dpp(__float_as_int(x), 0x141, 0xF, 0xF, false); // row_half_mirror (^7)
    x = fminf(x, __int_as_float(i));
    i = __builtin_amdgcn_mov_dpp(__float_as_int(x), 0x1B, 0xF, 0xF, false);  // quad reverse (^3)
    x = fminf(x, __int_as_float(i));
    i = __builtin_amdgcn_mov_dpp(__float_as_int(x), 0xB1, 0xF, 0xF, false);  // quad swap (^1)
    x = fminf(x, __int_as_float(i));
    return x;
}

// ---- merged prep: convert (768 blk) | P (64 blk, coalesced) | e2 (16 blk) ----
__global__ void prep(const float* __restrict__ rel,  const float* __restrict__ arg1,
                     const float* __restrict__ arg2, const float* __restrict__ frel,
                     const float* __restrict__ fa1,  const float* __restrict__ fa2,
                     const float* __restrict__ ent) {
    __shared__ float sF[64 * 101];              // 25.9 KB, stride 101 (2-way bank max)
    const int bx = blockIdx.x;
    const int t  = threadIdx.x;

    if (bx < CONVB) {
        // fp32 [4000][100] -> bf16 [4096][128], one short8 (8 cols) per thread
        int plane = bx >> 8;                    // 256 blocks per plane
        int local = ((bx & 255) << 8) | t;      // 0 .. NP*16-1
        int row = local >> 4, j = local & 15;   // j = 8-col chunk
        const float* src = (plane == 0) ? ent : (plane == 1) ? fa1 : fa2;
        unsigned short* dst = (plane == 0) ? g_A : (plane == 1) ? g_B1 : g_B2;
        short8 o = (short8){0, 0, 0, 0, 0, 0, 0, 0};
        if (row < NF && j <= 12) {
            if (j < 12) {
                float4 v0 = *(const float4*)(src + row * EDIM + j * 8);
                float4 v1 = *(const float4*)(src + row * EDIM + j * 8 + 4);
                o[0] = (short)f2bf(v0.x); o[1] = (short)f2bf(v0.y);
                o[2] = (short)f2bf(v0.z); o[3] = (short)f2bf(v0.w);
                o[4] = (short)f2bf(v1.x); o[5] = (short)f2bf(v1.y);
                o[6] = (short)f2bf(v1.z); o[7] = (short)f2bf(v1.w);
            } else {  // j == 12: cols 96..99 valid, 100..103 zero
                float4 v0 = *(const float4*)(src + row * EDIM + 96);
                o[0] = (short)f2bf(v0.x); o[1] = (short)f2bf(v0.y);
                o[2] = (short)f2bf(v0.z); o[3] = (short)f2bf(v0.w);
            }
        }
        *(short8*)(dst + row * KP + j * 8) = o;
    } else if (bx < CONVB + PREPB) {
        // P for one 64-f group, ALL 8 b's.  3 passes (frel/fa1/fa2): stage 64x100
        // floats coalesced into LDS, then thread (fl = t&63, bq = t>>6) computes
        // dots for b = bq and bq+4 via LDS broadcast + wave-uniform s_loads.
        const int fbx = bx - CONVB;             // 0..63
        const int fl = t & 63;
        const int bq = t >> 6;                  // 0..3; owns b = bq, bq+4
        const int f  = fbx * 64 + fl;

        float nf = 0.f;
        float dr[2], d1[2], d2[2], qr[2], q1n[2], q2n[2];

        #pragma unroll 3
        for (int pass = 0; pass < 3; pass++) {
            const float* src = (pass == 0) ? frel : (pass == 1) ? fa1 : fa2;
            const float* qv  = (pass == 0) ? rel  : (pass == 1) ? arg1 : arg2;
            __syncthreads();                    // previous pass's reads done
            #pragma unroll
            for (int i = 0; i < 25; i++) {      // 6400 floats, coalesced
                int idx = i * 256 + t;
                int row = idx / 100, col = idx - row * 100;
                int fr = fbx * 64 + row; if (fr > NF - 1) fr = NF - 1;
                sF[row * 101 + col] = src[fr * EDIM + col];
            }
            __syncthreads();
            float dot0 = 0.f, dot1 = 0.f, qn0 = 0.f, qn1 = 0.f, fn = 0.f;
            #pragma unroll 4
            for (int k = 0; k < EDIM; k++) {
                float fv = sF[fl * 101 + k];
                float u0 = qv[bq * EDIM + k];          // wave-uniform -> s_load
                float u1 = qv[(bq + 4) * EDIM + k];
                dot0 = fmaf(fv, u0, dot0);
                dot1 = fmaf(fv, u1, dot1);
                qn0  = fmaf(u0, u0, qn0);
                qn1  = fmaf(u1, u1, qn1);
                fn   = fmaf(fv, fv, fn);
            }
            nf += fn;
            if (pass == 0) { dr[0] = dot0; dr[1] = dot1; qr[0] = qn0; qr[1] = qn1; }
            else if (pass == 1) { d1[0] = dot0; d1[1] = dot1; q1n[0] = qn0; q1n[1] = qn1; }
            else { d2[0] = dot0; d2[1] = dot1; q2n[0] = qn0; q2n[1] = qn1; }
        }

        const int cc = fl & 15;                 // f & 15
        const int ft = fl >> 4;                 // (f & 63) >> 4
        #pragma unroll
        for (int bi = 0; bi < 2; bi++) {
            int b = bq + bi * 4;
            float psp = nf + qr[bi] + q1n[bi] - 2.f * (dr[bi] + d1[bi]);
            float ppo = nf + qr[bi] + q2n[bi] - 2.f * (dr[bi] + d2[bi]);
            if (f >= NF) { psp = __builtin_inff(); ppo = __builtin_inff(); }
            int chunk = cc * 8 + (b ^ (cc & 7));
            g_P2[(0 * 64 + fbx) * 512 + chunk * 4 + ft] = psp;
            g_P2[(1 * 64 + fbx) * 512 + chunk * 4 + ft] = ppo;
        }
    } else {
        int n = (bx - CONVB - PREPB) * 256 + t;
        if (n < NN) {
            const float4* ep = (const float4*)(ent + n * EDIM);
            float s = 0.f;
            #pragma unroll
            for (int i = 0; i < EDIM / 4; i++) {
                float4 v = ep[i];
                s += v.x * v.x + v.y * v.y + v.z * v.z + v.w * v.w;
            }
            g_e2[n] = s;
        }
    }
}

// Main: grid (32, 16, 2); z = g.  Per block: 128 n-rows, FPB=4 f-blocks of 64.
// A fragments hoisted in registers (direct global loads, no LDS).
// B + P double-buffered in LDS via global_load_lds (pre-swizzled source).
// P folded in MFMA acc layout; running min in 64 VGPRs; DPP c-reduce at end.
// launch_bounds(256,3): 36 KB LDS x3 = 108 <= 160 KB; VGPR cap 168.
__global__ void __launch_bounds__(256, 3) main_kernel() {
    __shared__ __align__(16) unsigned short sB[2][BF * 128]; // 2 x 16 KB, chunk-swizzled
    __shared__ __align__(16) float sP[2][512];               // 2 x 2 KB

    const int t = threadIdx.x;
    const int n0 = blockIdx.x * BN;
    const int by = blockIdx.y;
    const int g  = blockIdx.z;
    const int lane = t & 63;
    const int c = lane & 15;
    const int q = lane >> 4;
    const int w = t >> 6;
    const int w32 = w * 32;

    const unsigned short* gB = g ? g_B1 : g_B2;  // g=0(sp): entity . fa2; g=1(po): . fa1

    // ---- A fragments direct from global, hoisted across all f-blocks ----
    short8 afrag[2][4];                          // [mt][s]  (32 VGPR)
    #pragma unroll
    for (int mt = 0; mt < 2; mt++)
        #pragma unroll
        for (int s = 0; s < 4; s++)
            afrag[mt][s] = *(const short8*)(g_A + (n0 + w32 + mt * 16 + c) * KP + (s * 4 + q) * 8);

    floatx4 m2[NB][2];                           // [b][mt] running min (64 VGPR)
    #pragma unroll
    for (int b = 0; b < NB; b++)
        #pragma unroll
        for (int mt = 0; mt < 2; mt++)
            m2[b][mt] = (floatx4){__builtin_inff(), __builtin_inff(),
                                  __builtin_inff(), __builtin_inff()};

    // DMA-stage B tile (16 KB) + P (2 KB) for f-block fb into buffer buf.
    // LDS dest is linear (wave base + lane*16); swizzle folded into global source.
    auto stage = [&](int buf, int fb) {
        const int f0r = fb * BF;
        #pragma unroll
        for (int j = 0; j < 4; j++) {
            int ck = (w * 4 + j) * 64 + lane;                 // dest chunk index
            int rw = ck >> 4, ch = ck & 15;
            int src = (f0r + rw) * 16 + (ch ^ (rw & 15));     // source chunk (pre-swizzle)
            __builtin_amdgcn_global_load_lds(
                (gas_u32)(gB + src * 8),
                (las_u32)(&sB[buf][(w * 4 + j) * 512]),
                16, 0, 0);
        }
        if (w < 2)
            __builtin_amdgcn_global_load_lds(
                (gas_u32)(g_P2 + (g * 64 + fb) * 512 + w * 256 + lane * 4),
                (las_u32)(&sP[buf][w * 256]),
                16, 0, 0);
    };

    stage(0, by * FPB);
    __syncthreads();   // vmcnt(0) drain: buffer 0 ready

    #pragma unroll 1
    for (int ib = 0; ib < FPB; ib++) {
        const int cur = ib & 1;
        if (ib + 1 < FPB) stage(cur ^ 1, by * FPB + ib + 1);  // async, drains at barrier

        const short8* pB = (const short8*)sB[cur];
        floatx4 acc[2][4];                       // [mt][ft]
        #pragma unroll
        for (int mt = 0; mt < 2; mt++)
            #pragma unroll
            for (int ft = 0; ft < 4; ft++)
                acc[mt][ft] = (floatx4){0.f, 0.f, 0.f, 0.f};

        #pragma unroll
        for (int s = 0; s < 4; s++) {            // K-steps of 32
            const int base = s * 4 + q;
            #pragma unroll
            for (int ft = 0; ft < 4; ft++) {
                short8 bb = pB[(ft * 16 + c) * 16 + (base ^ c)];
                acc[0][ft] = __builtin_amdgcn_mfma_f32_16x16x32_bf16(afrag[0][s], bb, acc[0][ft], 0, 0, 0);
                acc[1][ft] = __builtin_amdgcn_mfma_f32_16x16x32_bf16(afrag[1][s], bb, acc[1][ft], 0, 0, 0);
            }
        }

        // ---- fold P in acc layout: f = ft*16 + c; one b128 per b ----
        const float* Pf = sP[cur];
        #pragma unroll
        for (int b = 0; b < NB; b++) {
            floatx4 p = *(const floatx4*)(Pf + (c * 8 + (b ^ (c & 7))) * 4);
            #pragma unroll
            for (int mt = 0; mt < 2; mt++) {
                #pragma unroll
                for (int r = 0; r < 4; r++) {
                    float t0 = fmaf(-2.f, acc[mt][0][r], p[0]);
                    float t1 = fmaf(-2.f, acc[mt][1][r], p[1]);
                    float t2 = fmaf(-2.f, acc[mt][2][r], p[2]);
                    float t3 = fmaf(-2.f, acc[mt][3][r], p[3]);
                    float u = fminf(fminf(t0, t1), t2);                   // v_min3
                    m2[b][mt][r] = fminf(fminf(u, t3), m2[b][mt][r]);     // v_min3
                }
            }
        }
        if (ib + 1 < FPB) __syncthreads();       // next buffer staged + this one reusable
    }

    // ---- once: reduce over 16 c-lanes (DPP, pure VALU) ----
    #pragma unroll
    for (int b = 0; b < NB; b++)
        #pragma unroll
        for (int mt = 0; mt < 2; mt++)
            #pragma unroll
            for (int r = 0; r < 4; r++)
                m2[b][mt][r] = row16_min(m2[b][mt][r]);

    if (c == 0) {
        #pragma unroll
        for (int b = 0; b < NB; b++)
            #pragma unroll
            for (int mt = 0; mt < 2; mt++)
                *(float4*)&g_part[((g * NB + b) * NYB + by) * NP +
                                  n0 + w32 + mt * 16 + q * 4] =
                    (float4){m2[b][mt][0], m2[b][mt][1], m2[b][mt][2], m2[b][mt][3]};
    }
}

__global__ void finalize(float* __restrict__ out) {
    int idx = blockIdx.x * 256 + threadIdx.x;   // over 2*NB*NN, out layout (g*NB+b)*NN+n
    if (idx >= 2 * NB * NN) return;
    int sb = idx / NN;
    int n = idx % NN;
    float m = __builtin_inff();
    #pragma unroll
    for (int j = 0; j < NYB; j += 2) {
        float a = g_part[(sb * NYB + j) * NP + n];
        float b = g_part[(sb * NYB + j + 1) * NP + n];
        m = fminf(m, fminf(a, b));              // v_min3
    }
    float d2 = fmaxf(m + g_e2[n], 0.f);
    out[idx] = expf(-0.5f * d2);
}

extern "C" void kernel_launch(void* const* d_in, const int* in_sizes, int n_in,
                              void* d_out, int out_size, void* d_ws, size_t ws_size,
                              hipStream_t stream) {
    const float* rel  = (const float*)d_in[0];
    const float* arg1 = (const float*)d_in[1];
    const float* arg2 = (const float*)d_in[2];
    const float* frel = (const float*)d_in[3];
    const float* fa1  = (const float*)d_in[4];
    const float* fa2  = (const float*)d_in[5];
    const float* ent  = (const float*)d_in[6];
    float* out = (float*)d_out;

    prep<<<dim3(CONVB + PREPB + E2B), 256, 0, stream>>>(rel, arg1, arg2, frel, fa1, fa2, ent);
    main_kernel<<<dim3(NP / BN, NYB, 2), 256, 0, stream>>>();
    finalize<<<(2 * NB * NN + 255) / 256, 256, 0, stream>>>(out);
}

// Round 8
// 112.431 us; speedup vs baseline: 1.3108x; 1.1279x over previous
//
#include <hip/hip_runtime.h>
#include <math.h>

#define EDIM 100
#define KP   128          // padded K
#define NF   4000
#define NN   4000
#define NB   8
#define NP   4096         // padded N and F
#define BN   128          // n-rows per block
#define BF   64           // f per f-block
#define FPB  8            // f-blocks folded per main block
#define NYB  8            // 64 f-blocks / FPB

#define CONVB (3 * NP * 16 / 256)     // 768 convert blocks (short8 per thread)
#define PREPB 64                      // 64 P-blocks (one per 64-f group, all 8 b's)
#define E2B   ((NN + 255) / 256)      // 16 e2 blocks

typedef __attribute__((ext_vector_type(8))) short short8;
typedef __attribute__((ext_vector_type(4))) float floatx4;

typedef const __attribute__((address_space(1))) unsigned int* gas_u32;
typedef __attribute__((address_space(3))) unsigned int* las_u32;

// Static device scratch.
__device__ __align__(16) unsigned short g_A [NP * KP];   // ent  bf16, K-padded
__device__ __align__(16) unsigned short g_B1[NP * KP];   // fa1  bf16
__device__ __align__(16) unsigned short g_B2[NP * KP];   // fa2  bf16
// P in main-ready layout: [g][fblk 64][chunk 128][ft 4] floats.
// chunk = c*8 + (b ^ (c&7))  -- XOR spreads the LDS fold-read across banks.
__device__ __align__(16) float g_P2[2 * 64 * 512];
__device__ float g_e2[NN];
__device__ float g_part[2 * NB * NYB * NP];              // [g][b][yblk][n]  (2 MB)

__device__ __forceinline__ unsigned short f2bf(float x) {
    union { float f; unsigned int u; } v; v.f = x;
    unsigned int r = v.u + 0x7FFFu + ((v.u >> 16) & 1u);  // RNE
    return (unsigned short)(r >> 16);
}

// 16-lane min reduction via DPP mirrors: XOR-masks {15,7,3,1} span all 16 lanes.
__device__ __forceinline__ float row16_min(float x) {
    int i;
    i = __builtin_amdgcn_mov_dpp(__float_as_int(x), 0x140, 0xF, 0xF, false); // row_mirror (^15)
    x = fminf(x, __int_as_float(i));
    i = __builtin_amdgcn_mov_dpp(__float_as_int(x), 0x141, 0xF, 0xF, false); // row_half_mirror (^7)
    x = fminf(x, __int_as_float(i));
    i = __builtin_amdgcn_mov_dpp(__float_as_int(x), 0x1B, 0xF, 0xF, false);  // quad reverse (^3)
    x = fminf(x, __int_as_float(i));
    i = __builtin_amdgcn_mov_dpp(__float_as_int(x), 0xB1, 0xF, 0xF, false);  // quad swap (^1)
    x = fminf(x, __int_as_float(i));
    return x;
}

// ---- merged prep: convert (768 blk) | P (64 blk, coalesced) | e2 (16 blk) ----
__global__ void prep(const float* __restrict__ rel,  const float* __restrict__ arg1,
                     const float* __restrict__ arg2, const float* __restrict__ frel,
                     const float* __restrict__ fa1,  const float* __restrict__ fa2,
                     const float* __restrict__ ent) {
    __shared__ float sF[64 * 101];              // 25.9 KB, stride 101 (2-way bank max)
    const int bx = blockIdx.x;
    const int t  = threadIdx.x;

    if (bx < CONVB) {
        // fp32 [4000][100] -> bf16 [4096][128], one short8 (8 cols) per thread
        int plane = bx >> 8;                    // 256 blocks per plane
        int local = ((bx & 255) << 8) | t;      // 0 .. NP*16-1
        int row = local >> 4, j = local & 15;   // j = 8-col chunk
        const float* src = (plane == 0) ? ent : (plane == 1) ? fa1 : fa2;
        unsigned short* dst = (plane == 0) ? g_A : (plane == 1) ? g_B1 : g_B2;
        short8 o = (short8){0, 0, 0, 0, 0, 0, 0, 0};
        if (row < NF && j <= 12) {
            if (j < 12) {
                float4 v0 = *(const float4*)(src + row * EDIM + j * 8);
                float4 v1 = *(const float4*)(src + row * EDIM + j * 8 + 4);
                o[0] = (short)f2bf(v0.x); o[1] = (short)f2bf(v0.y);
                o[2] = (short)f2bf(v0.z); o[3] = (short)f2bf(v0.w);
                o[4] = (short)f2bf(v1.x); o[5] = (short)f2bf(v1.y);
                o[6] = (short)f2bf(v1.z); o[7] = (short)f2bf(v1.w);
            } else {  // j == 12: cols 96..99 valid, 100..103 zero
                float4 v0 = *(const float4*)(src + row * EDIM + 96);
                o[0] = (short)f2bf(v0.x); o[1] = (short)f2bf(v0.y);
                o[2] = (short)f2bf(v0.z); o[3] = (short)f2bf(v0.w);
            }
        }
        *(short8*)(dst + row * KP + j * 8) = o;
    } else if (bx < CONVB + PREPB) {
        // P for one 64-f group, ALL 8 b's.  3 passes (frel/fa1/fa2): stage 64x100
        // floats coalesced into LDS, then thread (fl = t&63, bq = t>>6) computes
        // dots for b = bq and bq+4 via LDS broadcast + wave-uniform s_loads.
        const int fbx = bx - CONVB;             // 0..63
        const int fl = t & 63;
        const int bq = t >> 6;                  // 0..3; owns b = bq, bq+4
        const int f  = fbx * 64 + fl;

        float nf = 0.f;
        float dr[2], d1[2], d2[2], qr[2], q1n[2], q2n[2];

        #pragma unroll 3
        for (int pass = 0; pass < 3; pass++) {
            const float* src = (pass == 0) ? frel : (pass == 1) ? fa1 : fa2;
            const float* qv  = (pass == 0) ? rel  : (pass == 1) ? arg1 : arg2;
            __syncthreads();                    // previous pass's reads done
            #pragma unroll
            for (int i = 0; i < 25; i++) {      // 6400 floats, coalesced
                int idx = i * 256 + t;
                int row = idx / 100, col = idx - row * 100;
                int fr = fbx * 64 + row; if (fr > NF - 1) fr = NF - 1;
                sF[row * 101 + col] = src[fr * EDIM + col];
            }
            __syncthreads();
            float dot0 = 0.f, dot1 = 0.f, qn0 = 0.f, qn1 = 0.f, fn = 0.f;
            #pragma unroll 4
            for (int k = 0; k < EDIM; k++) {
                float fv = sF[fl * 101 + k];
                float u0 = qv[bq * EDIM + k];          // wave-uniform -> s_load
                float u1 = qv[(bq + 4) * EDIM + k];
                dot0 = fmaf(fv, u0, dot0);
                dot1 = fmaf(fv, u1, dot1);
                qn0  = fmaf(u0, u0, qn0);
                qn1  = fmaf(u1, u1, qn1);
                fn   = fmaf(fv, fv, fn);
            }
            nf += fn;
            if (pass == 0) { dr[0] = dot0; dr[1] = dot1; qr[0] = qn0; qr[1] = qn1; }
            else if (pass == 1) { d1[0] = dot0; d1[1] = dot1; q1n[0] = qn0; q1n[1] = qn1; }
            else { d2[0] = dot0; d2[1] = dot1; q2n[0] = qn0; q2n[1] = qn1; }
        }

        const int cc = fl & 15;                 // f & 15
        const int ft = fl >> 4;                 // (f & 63) >> 4
        #pragma unroll
        for (int bi = 0; bi < 2; bi++) {
            int b = bq + bi * 4;
            float psp = nf + qr[bi] + q1n[bi] - 2.f * (dr[bi] + d1[bi]);
            float ppo = nf + qr[bi] + q2n[bi] - 2.f * (dr[bi] + d2[bi]);
            if (f >= NF) { psp = __builtin_inff(); ppo = __builtin_inff(); }
            int chunk = cc * 8 + (b ^ (cc & 7));
            g_P2[(0 * 64 + fbx) * 512 + chunk * 4 + ft] = psp;
            g_P2[(1 * 64 + fbx) * 512 + chunk * 4 + ft] = ppo;
        }
    } else {
        int n = (bx - CONVB - PREPB) * 256 + t;
        if (n < NN) {
            const float4* ep = (const float4*)(ent + n * EDIM);
            float s = 0.f;
            #pragma unroll
            for (int i = 0; i < EDIM / 4; i++) {
                float4 v = ep[i];
                s += v.x * v.x + v.y * v.y + v.z * v.z + v.w * v.w;
            }
            g_e2[n] = s;
        }
    }
}

// Main: grid (32, 8, 2); z = g.  Per block: 128 n-rows, FPB=8 f-blocks of 64.
// 512 blocks = exactly one resident round at 2 blocks/CU.
// A fragments hoisted in registers (direct global loads, no LDS).
// B + P double-buffered in LDS via global_load_lds (pre-swizzled source).
// P folded in MFMA acc layout; running min in 64 VGPRs; DPP c-reduce at end.
// launch_bounds(256,2): VGPR cap 256 -- (256,3) forced VGPR=84 and spilled
// ~16 MB of scratch traffic (r6), costing +16 us.  Do not raise again.
__global__ void __launch_bounds__(256, 2) main_kernel() {
    __shared__ __align__(16) unsigned short sB[2][BF * 128]; // 2 x 16 KB, chunk-swizzled
    __shared__ __align__(16) float sP[2][512];               // 2 x 2 KB

    const int t = threadIdx.x;
    const int n0 = blockIdx.x * BN;
    const int by = blockIdx.y;
    const int g  = blockIdx.z;
    const int lane = t & 63;
    const int c = lane & 15;
    const int q = lane >> 4;
    const int w = t >> 6;
    const int w32 = w * 32;

    const unsigned short* gB = g ? g_B1 : g_B2;  // g=0(sp): entity . fa2; g=1(po): . fa1

    // ---- A fragments direct from global, hoisted across all f-blocks ----
    short8 afrag[2][4];                          // [mt][s]  (32 VGPR)
    #pragma unroll
    for (int mt = 0; mt < 2; mt++)
        #pragma unroll
        for (int s = 0; s < 4; s++)
            afrag[mt][s] = *(const short8*)(g_A + (n0 + w32 + mt * 16 + c) * KP + (s * 4 + q) * 8);

    floatx4 m2[NB][2];                           // [b][mt] running min (64 VGPR)
    #pragma unroll
    for (int b = 0; b < NB; b++)
        #pragma unroll
        for (int mt = 0; mt < 2; mt++)
            m2[b][mt] = (floatx4){__builtin_inff(), __builtin_inff(),
                                  __builtin_inff(), __builtin_inff()};

    // DMA-stage B tile (16 KB) + P (2 KB) for f-block fb into buffer buf.
    // LDS dest is linear (wave base + lane*16); swizzle folded into global source.
    auto stage = [&](int buf, int fb) {
        const int f0r = fb * BF;
        #pragma unroll
        for (int j = 0; j < 4; j++) {
            int ck = (w * 4 + j) * 64 + lane;                 // dest chunk index
            int rw = ck >> 4, ch = ck & 15;
            int src = (f0r + rw) * 16 + (ch ^ (rw & 15));     // source chunk (pre-swizzle)
            __builtin_amdgcn_global_load_lds(
                (gas_u32)(gB + src * 8),
                (las_u32)(&sB[buf][(w * 4 + j) * 512]),
                16, 0, 0);
        }
        if (w < 2)
            __builtin_amdgcn_global_load_lds(
                (gas_u32)(g_P2 + (g * 64 + fb) * 512 + w * 256 + lane * 4),
                (las_u32)(&sP[buf][w * 256]),
                16, 0, 0);
    };

    stage(0, by * FPB);
    __syncthreads();   // vmcnt(0) drain: buffer 0 ready

    #pragma unroll 1
    for (int ib = 0; ib < FPB; ib++) {
        const int cur = ib & 1;
        if (ib + 1 < FPB) stage(cur ^ 1, by * FPB + ib + 1);  // async, drains at barrier

        const short8* pB = (const short8*)sB[cur];
        floatx4 acc[2][4];                       // [mt][ft]
        #pragma unroll
        for (int mt = 0; mt < 2; mt++)
            #pragma unroll
            for (int ft = 0; ft < 4; ft++)
                acc[mt][ft] = (floatx4){0.f, 0.f, 0.f, 0.f};

        #pragma unroll
        for (int s = 0; s < 4; s++) {            // K-steps of 32
            const int base = s * 4 + q;
            #pragma unroll
            for (int ft = 0; ft < 4; ft++) {
                short8 bb = pB[(ft * 16 + c) * 16 + (base ^ c)];
                acc[0][ft] = __builtin_amdgcn_mfma_f32_16x16x32_bf16(afrag[0][s], bb, acc[0][ft], 0, 0, 0);
                acc[1][ft] = __builtin_amdgcn_mfma_f32_16x16x32_bf16(afrag[1][s], bb, acc[1][ft], 0, 0, 0);
            }
        }

        // ---- fold P in acc layout: f = ft*16 + c; one b128 per b ----
        const float* Pf = sP[cur];
        #pragma unroll
        for (int b = 0; b < NB; b++) {
            floatx4 p = *(const floatx4*)(Pf + (c * 8 + (b ^ (c & 7))) * 4);
            #pragma unroll
            for (int mt = 0; mt < 2; mt++) {
                #pragma unroll
                for (int r = 0; r < 4; r++) {
                    float t0 = fmaf(-2.f, acc[mt][0][r], p[0]);
                    float t1 = fmaf(-2.f, acc[mt][1][r], p[1]);
                    float t2 = fmaf(-2.f, acc[mt][2][r], p[2]);
                    float t3 = fmaf(-2.f, acc[mt][3][r], p[3]);
                    float u = fminf(fminf(t0, t1), t2);                   // v_min3
                    m2[b][mt][r] = fminf(fminf(u, t3), m2[b][mt][r]);     // v_min3
                }
            }
        }
        if (ib + 1 < FPB) __syncthreads();       // next buffer staged + this one reusable
    }

    // ---- once: reduce over 16 c-lanes (DPP, pure VALU) ----
    #pragma unroll
    for (int b = 0; b < NB; b++)
        #pragma unroll
        for (int mt = 0; mt < 2; mt++)
            #pragma unroll
            for (int r = 0; r < 4; r++)
                m2[b][mt][r] = row16_min(m2[b][mt][r]);

    if (c == 0) {
        #pragma unroll
        for (int b = 0; b < NB; b++)
            #pragma unroll
            for (int mt = 0; mt < 2; mt++)
                *(float4*)&g_part[((g * NB + b) * NYB + by) * NP +
                                  n0 + w32 + mt * 16 + q * 4] =
                    (float4){m2[b][mt][0], m2[b][mt][1], m2[b][mt][2], m2[b][mt][3]};
    }
}

__global__ void finalize(float* __restrict__ out) {
    int idx = blockIdx.x * 256 + threadIdx.x;   // over 2*NB*NN, out layout (g*NB+b)*NN+n
    if (idx >= 2 * NB * NN) return;
    int sb = idx / NN;
    int n = idx % NN;
    float m = __builtin_inff();
    #pragma unroll
    for (int j = 0; j < NYB; j += 2) {
        float a = g_part[(sb * NYB + j) * NP + n];
        float b = g_part[(sb * NYB + j + 1) * NP + n];
        m = fminf(m, fminf(a, b));              // v_min3
    }
    float d2 = fmaxf(m + g_e2[n], 0.f);
    out[idx] = expf(-0.5f * d2);
}

extern "C" void kernel_launch(void* const* d_in, const int* in_sizes, int n_in,
                              void* d_out, int out_size, void* d_ws, size_t ws_size,
                              hipStream_t stream) {
    const float* rel  = (const float*)d_in[0];
    const float* arg1 = (const float*)d_in[1];
    const float* arg2 = (const float*)d_in[2];
    const float* frel = (const float*)d_in[3];
    const float* fa1  = (const float*)d_in[4];
    const float* fa2  = (const float*)d_in[5];
    const float* ent  = (const float*)d_in[6];
    float* out = (float*)d_out;

    prep<<<dim3(CONVB + PREPB + E2B), 256, 0, stream>>>(rel, arg1, arg2, frel, fa1, fa2, ent);
    main_kernel<<<dim3(NP / BN, NYB, 2), 256, 0, stream>>>();
    finalize<<<(2 * NB * NN + 255) / 256, 256, 0, stream>>>(out);
}

// Round 9
// 110.236 us; speedup vs baseline: 1.3369x; 1.0199x over previous
//
#include <hip/hip_runtime.h>
#include <math.h>

#define EDIM 100
#define KP   128          // padded K
#define NF   4000
#define NN   4000
#define NB   8
#define NP   4096         // padded N and F
#define BN   128          // n-rows per block
#define BF   64           // f per f-block
#define FPB  8            // f-blocks folded per main block
#define NYB  8            // 64 f-blocks / FPB

#define CONVB (3 * NP * 16 / 256)     // 768 convert blocks (short8 per thread)
#define PREPB 64                      // 64 P-blocks (one per 64-f group, all 8 b's)
#define E2B   ((NN + 255) / 256)      // 16 e2 blocks

typedef __attribute__((ext_vector_type(8))) short short8;
typedef __attribute__((ext_vector_type(4))) float floatx4;

typedef const __attribute__((address_space(1))) unsigned int* gas_u32;
typedef __attribute__((address_space(3))) unsigned int* las_u32;

// Static device scratch.
__device__ __align__(16) unsigned short g_A [NP * KP];   // ent  bf16, K-padded
__device__ __align__(16) unsigned short g_B1[NP * KP];   // fa1  bf16
__device__ __align__(16) unsigned short g_B2[NP * KP];   // fa2  bf16
// P in main-ready layout: [g][fblk 64][chunk 128][ft 4] floats.
// chunk = c*8 + (b ^ (c&7))  -- XOR spreads the LDS fold-read across banks.
__device__ __align__(16) float g_P2[2 * 64 * 512];
__device__ float g_e2[NN];
__device__ float g_part[2 * NB * NYB * NP];              // [g][b][yblk][n]  (2 MB)

__device__ __forceinline__ unsigned short f2bf(float x) {
    union { float f; unsigned int u; } v; v.f = x;
    unsigned int r = v.u + 0x7FFFu + ((v.u >> 16) & 1u);  // RNE
    return (unsigned short)(r >> 16);
}

// 16-lane min reduction via DPP mirrors: XOR-masks {15,7,3,1} span all 16 lanes.
__device__ __forceinline__ float row16_min(float x) {
    int i;
    i = __builtin_amdgcn_mov_dpp(__float_as_int(x), 0x140, 0xF, 0xF, false); // row_mirror (^15)
    x = fminf(x, __int_as_float(i));
    i = __builtin_amdgcn_mov_dpp(__float_as_int(x), 0x141, 0xF, 0xF, false); // row_half_mirror (^7)
    x = fminf(x, __int_as_float(i));
    i = __builtin_amdgcn_mov_dpp(__float_as_int(x), 0x1B, 0xF, 0xF, false);  // quad reverse (^3)
    x = fminf(x, __int_as_float(i));
    i = __builtin_amdgcn_mov_dpp(__float_as_int(x), 0xB1, 0xF, 0xF, false);  // quad swap (^1)
    x = fminf(x, __int_as_float(i));
    return x;
}

// ---- merged prep: convert (768 blk) | P (64 blk, coalesced) | e2 (16 blk) ----
__global__ void prep(const float* __restrict__ rel,  const float* __restrict__ arg1,
                     const float* __restrict__ arg2, const float* __restrict__ frel,
                     const float* __restrict__ fa1,  const float* __restrict__ fa2,
                     const float* __restrict__ ent) {
    __shared__ float sF[64 * 101];              // 25.9 KB, stride 101 (2-way bank max)
    const int bx = blockIdx.x;
    const int t  = threadIdx.x;

    if (bx < CONVB) {
        // fp32 [4000][100] -> bf16 [4096][128], one short8 (8 cols) per thread
        int plane = bx >> 8;                    // 256 blocks per plane
        int local = ((bx & 255) << 8) | t;      // 0 .. NP*16-1
        int row = local >> 4, j = local & 15;   // j = 8-col chunk
        const float* src = (plane == 0) ? ent : (plane == 1) ? fa1 : fa2;
        unsigned short* dst = (plane == 0) ? g_A : (plane == 1) ? g_B1 : g_B2;
        short8 o = (short8){0, 0, 0, 0, 0, 0, 0, 0};
        if (row < NF && j <= 12) {
            if (j < 12) {
                float4 v0 = *(const float4*)(src + row * EDIM + j * 8);
                float4 v1 = *(const float4*)(src + row * EDIM + j * 8 + 4);
                o[0] = (short)f2bf(v0.x); o[1] = (short)f2bf(v0.y);
                o[2] = (short)f2bf(v0.z); o[3] = (short)f2bf(v0.w);
                o[4] = (short)f2bf(v1.x); o[5] = (short)f2bf(v1.y);
                o[6] = (short)f2bf(v1.z); o[7] = (short)f2bf(v1.w);
            } else {  // j == 12: cols 96..99 valid, 100..103 zero
                float4 v0 = *(const float4*)(src + row * EDIM + 96);
                o[0] = (short)f2bf(v0.x); o[1] = (short)f2bf(v0.y);
                o[2] = (short)f2bf(v0.z); o[3] = (short)f2bf(v0.w);
            }
        }
        *(short8*)(dst + row * KP + j * 8) = o;
    } else if (bx < CONVB + PREPB) {
        // P for one 64-f group, ALL 8 b's.  3 passes (frel/fa1/fa2): stage 64x100
        // floats coalesced into LDS, then thread (fl = t&63, bq = t>>6) computes
        // dots for b = bq and bq+4 via LDS broadcast + wave-uniform s_loads.
        const int fbx = bx - CONVB;             // 0..63
        const int fl = t & 63;
        const int bq = t >> 6;                  // 0..3; owns b = bq, bq+4
        const int f  = fbx * 64 + fl;

        float nf = 0.f;
        float dr[2], d1[2], d2[2], qr[2], q1n[2], q2n[2];

        #pragma unroll 3
        for (int pass = 0; pass < 3; pass++) {
            const float* src = (pass == 0) ? frel : (pass == 1) ? fa1 : fa2;
            const float* qv  = (pass == 0) ? rel  : (pass == 1) ? arg1 : arg2;
            __syncthreads();                    // previous pass's reads done
            #pragma unroll
            for (int i = 0; i < 25; i++) {      // 6400 floats, coalesced
                int idx = i * 256 + t;
                int row = idx / 100, col = idx - row * 100;
                int fr = fbx * 64 + row; if (fr > NF - 1) fr = NF - 1;
                sF[row * 101 + col] = src[fr * EDIM + col];
            }
            __syncthreads();
            float dot0 = 0.f, dot1 = 0.f, qn0 = 0.f, qn1 = 0.f, fn = 0.f;
            #pragma unroll 4
            for (int k = 0; k < EDIM; k++) {
                float fv = sF[fl * 101 + k];
                float u0 = qv[bq * EDIM + k];          // wave-uniform -> s_load
                float u1 = qv[(bq + 4) * EDIM + k];
                dot0 = fmaf(fv, u0, dot0);
                dot1 = fmaf(fv, u1, dot1);
                qn0  = fmaf(u0, u0, qn0);
                qn1  = fmaf(u1, u1, qn1);
                fn   = fmaf(fv, fv, fn);
            }
            nf += fn;
            if (pass == 0) { dr[0] = dot0; dr[1] = dot1; qr[0] = qn0; qr[1] = qn1; }
            else if (pass == 1) { d1[0] = dot0; d1[1] = dot1; q1n[0] = qn0; q1n[1] = qn1; }
            else { d2[0] = dot0; d2[1] = dot1; q2n[0] = qn0; q2n[1] = qn1; }
        }

        const int cc = fl & 15;                 // f & 15
        const int ft = fl >> 4;                 // (f & 63) >> 4
        #pragma unroll
        for (int bi = 0; bi < 2; bi++) {
            int b = bq + bi * 4;
            float psp = nf + qr[bi] + q1n[bi] - 2.f * (dr[bi] + d1[bi]);
            float ppo = nf + qr[bi] + q2n[bi] - 2.f * (dr[bi] + d2[bi]);
            if (f >= NF) { psp = __builtin_inff(); ppo = __builtin_inff(); }
            int chunk = cc * 8 + (b ^ (cc & 7));
            g_P2[(0 * 64 + fbx) * 512 + chunk * 4 + ft] = psp;
            g_P2[(1 * 64 + fbx) * 512 + chunk * 4 + ft] = ppo;
        }
    } else {
        int n = (bx - CONVB - PREPB) * 256 + t;
        if (n < NN) {
            const float4* ep = (const float4*)(ent + n * EDIM);
            float s = 0.f;
            #pragma unroll
            for (int i = 0; i < EDIM / 4; i++) {
                float4 v = ep[i];
                s += v.x * v.x + v.y * v.y + v.z * v.z + v.w * v.w;
            }
            g_e2[n] = s;
        }
    }
}

// Main: grid (32, 8, 2), 512 threads (8 waves); z = g.  Per block: 128 n-rows,
// FPB=8 f-blocks of 64.  512 blocks = 2 blocks/CU, one resident round,
// 16 waves/CU = 4 waves/SIMD (r8 had 2/SIMD and >60% issue-idle; per-wave
// state halved via mt removal: each wave owns 16 n-rows).
// A fragments hoisted in registers; B + P double-buffered in LDS via
// global_load_lds (pre-swizzled source); P folded in MFMA acc layout;
// running min in 32 VGPRs; DPP c-reduce at end.
// launch_bounds(512,4): VGPR cap 128.  Spill tripwire: WRITE_SIZE >> 2.2 MB.
__global__ void __launch_bounds__(512, 4) main_kernel() {
    __shared__ __align__(16) unsigned short sB[2][BF * 128]; // 2 x 16 KB, chunk-swizzled
    __shared__ __align__(16) float sP[2][512];               // 2 x 2 KB

    const int t = threadIdx.x;
    const int n0 = blockIdx.x * BN;
    const int by = blockIdx.y;
    const int g  = blockIdx.z;
    const int lane = t & 63;
    const int c = lane & 15;
    const int q = lane >> 4;
    const int w = t >> 6;                        // 0..7
    const int w16 = w * 16;

    const unsigned short* gB = g ? g_B1 : g_B2;  // g=0(sp): entity . fa2; g=1(po): . fa1

    // ---- A fragments direct from global, hoisted across all f-blocks ----
    short8 afrag[4];                             // [s]  (16 VGPR)
    #pragma unroll
    for (int s = 0; s < 4; s++)
        afrag[s] = *(const short8*)(g_A + (n0 + w16 + c) * KP + (s * 4 + q) * 8);

    floatx4 m2[NB];                              // [b] running min (32 VGPR)
    #pragma unroll
    for (int b = 0; b < NB; b++)
        m2[b] = (floatx4){__builtin_inff(), __builtin_inff(),
                          __builtin_inff(), __builtin_inff()};

    // DMA-stage B tile (16 KB) + P (2 KB) for f-block fb into buffer buf.
    // LDS dest is linear (wave base + lane*16); swizzle folded into global source.
    auto stage = [&](int buf, int fb) {
        const int f0r = fb * BF;
        #pragma unroll
        for (int j = 0; j < 2; j++) {
            int ck = (w * 2 + j) * 64 + lane;                 // dest chunk index
            int rw = ck >> 4, ch = ck & 15;
            int src = (f0r + rw) * 16 + (ch ^ (rw & 15));     // source chunk (pre-swizzle)
            __builtin_amdgcn_global_load_lds(
                (gas_u32)(gB + src * 8),
                (las_u32)(&sB[buf][(w * 2 + j) * 512]),
                16, 0, 0);
        }
        if (w < 2)
            __builtin_amdgcn_global_load_lds(
                (gas_u32)(g_P2 + (g * 64 + fb) * 512 + w * 256 + lane * 4),
                (las_u32)(&sP[buf][w * 256]),
                16, 0, 0);
    };

    stage(0, by * FPB);
    __syncthreads();   // vmcnt(0) drain: buffer 0 ready

    #pragma unroll 1
    for (int ib = 0; ib < FPB; ib++) {
        const int cur = ib & 1;
        if (ib + 1 < FPB) stage(cur ^ 1, by * FPB + ib + 1);  // async, drains at barrier

        const short8* pB = (const short8*)sB[cur];
        floatx4 acc[4];                          // [ft]
        #pragma unroll
        for (int ft = 0; ft < 4; ft++)
            acc[ft] = (floatx4){0.f, 0.f, 0.f, 0.f};

        #pragma unroll
        for (int s = 0; s < 4; s++) {            // K-steps of 32
            const int base = s * 4 + q;
            #pragma unroll
            for (int ft = 0; ft < 4; ft++) {
                short8 bb = pB[(ft * 16 + c) * 16 + (base ^ c)];
                acc[ft] = __builtin_amdgcn_mfma_f32_16x16x32_bf16(afrag[s], bb, acc[ft], 0, 0, 0);
            }
        }

        // ---- fold P in acc layout: f = ft*16 + c; one b128 per b ----
        const float* Pf = sP[cur];
        #pragma unroll
        for (int b = 0; b < NB; b++) {
            floatx4 p = *(const floatx4*)(Pf + (c * 8 + (b ^ (c & 7))) * 4);
            #pragma unroll
            for (int r = 0; r < 4; r++) {
                float t0 = fmaf(-2.f, acc[0][r], p[0]);
                float t1 = fmaf(-2.f, acc[1][r], p[1]);
                float t2 = fmaf(-2.f, acc[2][r], p[2]);
                float t3 = fmaf(-2.f, acc[3][r], p[3]);
                float u = fminf(fminf(t0, t1), t2);               // v_min3
                m2[b][r] = fminf(fminf(u, t3), m2[b][r]);         // v_min3
            }
        }
        if (ib + 1 < FPB) __syncthreads();       // next buffer staged + this one reusable
    }

    // ---- once: reduce over 16 c-lanes (DPP, pure VALU) ----
    #pragma unroll
    for (int b = 0; b < NB; b++)
        #pragma unroll
        for (int r = 0; r < 4; r++)
            m2[b][r] = row16_min(m2[b][r]);

    if (c == 0) {
        #pragma unroll
        for (int b = 0; b < NB; b++)
            *(float4*)&g_part[((g * NB + b) * NYB + by) * NP + n0 + w16 + q * 4] =
                (float4){m2[b][0], m2[b][1], m2[b][2], m2[b][3]};
    }
}

__global__ void finalize(float* __restrict__ out) {
    int idx = blockIdx.x * 256 + threadIdx.x;   // over 2*NB*NN, out layout (g*NB+b)*NN+n
    if (idx >= 2 * NB * NN) return;
    int sb = idx / NN;
    int n = idx % NN;
    float m = __builtin_inff();
    #pragma unroll
    for (int j = 0; j < NYB; j += 2) {
        float a = g_part[(sb * NYB + j) * NP + n];
        float b = g_part[(sb * NYB + j + 1) * NP + n];
        m = fminf(m, fminf(a, b));              // v_min3
    }
    float d2 = fmaxf(m + g_e2[n], 0.f);
    out[idx] = expf(-0.5f * d2);
}

extern "C" void kernel_launch(void* const* d_in, const int* in_sizes, int n_in,
                              void* d_out, int out_size, void* d_ws, size_t ws_size,
                              hipStream_t stream) {
    const float* rel  = (const float*)d_in[0];
    const float* arg1 = (const float*)d_in[1];
    const float* arg2 = (const float*)d_in[2];
    const float* frel = (const float*)d_in[3];
    const float* fa1  = (const float*)d_in[4];
    const float* fa2  = (const float*)d_in[5];
    const float* ent  = (const float*)d_in[6];
    float* out = (float*)d_out;

    prep<<<dim3(CONVB + PREPB + E2B), 256, 0, stream>>>(rel, arg1, arg2, frel, fa1, fa2, ent);
    main_kernel<<<dim3(NP / BN, NYB, 2), 512, 0, stream>>>();
    finalize<<<(2 * NB * NN + 255) / 256, 256, 0, stream>>>(out);
}